// Round 23
// baseline (112.482 us; speedup 1.0000x reference)
//
#include <hip/hip_runtime.h>

#define D 64
#define ROWS 128   // tile rows per block (2 row-groups of 64)
#define TPB 256

typedef float f4 __attribute__((ext_vector_type(4)));
typedef short s8 __attribute__((ext_vector_type(8)));

static __device__ __forceinline__ unsigned short f2bf(float x) {
  union { float f; unsigned u; } v; v.f = x;
  return (unsigned short)((v.u + 0x7FFFu + ((v.u >> 16) & 1u)) >> 16);
}

static __device__ __forceinline__ s8 pack8(f4 a, f4 b) {
  s8 r;
  r[0] = (short)f2bf(a.x); r[1] = (short)f2bf(a.y);
  r[2] = (short)f2bf(a.z); r[3] = (short)f2bf(a.w);
  r[4] = (short)f2bf(b.x); r[5] = (short)f2bf(b.y);
  r[6] = (short)f2bf(b.z); r[7] = (short)f2bf(b.w);
  return r;
}

static __device__ __forceinline__ f4 fma4s(float a, f4 b, f4 c) {
  f4 r;
  r.x = fmaf(a, b.x, c.x);
  r.y = fmaf(a, b.y, c.y);
  r.z = fmaf(a, b.z, c.z);
  r.w = fmaf(a, b.w, c.w);
  return r;
}

static __device__ __forceinline__ f4 prelu4(f4 p, float a) {
  f4 r;
  r.x = p.x >= 0.0f ? p.x : a * p.x;
  r.y = p.y >= 0.0f ? p.y : a * p.y;
  r.z = p.z >= 0.0f ? p.z : a * p.z;
  r.w = p.w >= 0.0f ? p.w : a * p.w;
  return r;
}

static __device__ __forceinline__ float dot4(f4 x, f4 y, f4 z, float acc) {
  acc = fmaf(x.x + y.x, z.x, acc);
  acc = fmaf(x.y + y.y, z.y, acc);
  acc = fmaf(x.z + y.z, z.z, acc);
  acc = fmaf(x.w + y.w, z.w, acc);
  return acc;
}

static __device__ __forceinline__ f4 shfl4(f4 v, int src) {
  f4 r;
  r.x = __shfl(v.x, src);
  r.y = __shfl(v.y, src);
  r.z = __shfl(v.z, src);
  r.w = __shfl(v.w, src);
  return r;
}

// Raw asm 16B load with distinct dest (compiler cannot coalesce/serialize).
// HAZARD (R20): asm dests must never spill — keep VGPR cap margin >= ~50.
#define GLOAD(dst, ptr, OFF) \
  asm volatile("global_load_dwordx4 %0, %1, off offset:" #OFF \
               : "=v"(dst) : "v"(ptr))

// R23 = R22 with launch_bounds (256,3)->(256,4): residency cap 3->4
// blocks/CU. R22 proved the 2-tile/16-deep-burst structure holds at VGPR 76
// with zero spill (WRITE 125MB clean); its only deficit vs R19 was
// occupancy (29% vs 39%). Cap 128 vs 76 used = margin 52 (R20 hazard rule
// satisfied). Single-variable residency test on the amortized structure.
__global__ __launch_bounds__(TPB, 4) void dmc_fused(
    const float* __restrict__ h,
    const float* __restrict__ keys,
    const float* __restrict__ s,
    const float* __restrict__ U,
    const float* __restrict__ V,
    const float* __restrict__ W,
    const float* __restrict__ bias,
    const float* __restrict__ prelu_a,
    float* __restrict__ out,
    const int nblocks) {
  __shared__ __align__(16) unsigned short Ub[D * D];  // 8KB bf16, swizzled
  __shared__ __align__(16) unsigned short Vb[D * D];  // 8KB
  __shared__ __align__(16) float cc[D];

  const int tid  = threadIdx.x;
  const int lane = tid & 63;
  const int wv   = tid >> 6;            // 0..3
  const int g    = lane >> 4;           // 0..3
  const int rl   = lane & 15;           // MFMA n (batch row) / m (U row)
  const int j0   = blockIdx.x * ROWS;
  const int nrem = nblocks - j0;        // rows in this tile (<=128)

  const int r0   = wv * 16 + rl;        // row-group 0 row
  const int r1   = 64 + wv * 16 + rl;   // row-group 1 row
  const int rc0  = (r0 < nrem) ? r0 : (nrem - 1);
  const int rc1  = (r1 < nrem) ? r1 : (nrem - 1);

  // ---- 1) issue ALL 16 B-frag loads as one asm burst (16 dests, 4 bases) ----
  const f4* hB0 = reinterpret_cast<const f4*>(h + (size_t)(j0 + rc0) * D) + 2 * g;
  const f4* kB0 = reinterpret_cast<const f4*>(keys + (size_t)(j0 + rc0) * D) + 2 * g;
  const f4* hB1 = reinterpret_cast<const f4*>(h + (size_t)(j0 + rc1) * D) + 2 * g;
  const f4* kB1 = reinterpret_cast<const f4*>(keys + (size_t)(j0 + rc1) * D) + 2 * g;

  f4 ah0a, ah0b, ah1a, ah1b, ak0a, ak0b, ak1a, ak1b;   // group 0
  f4 bh0a, bh0b, bh1a, bh1b, bk0a, bk0b, bk1a, bk1b;   // group 1
  GLOAD(ah0a, hB0, 0);
  GLOAD(ah0b, hB0, 16);
  GLOAD(ah1a, hB0, 128);
  GLOAD(ah1b, hB0, 144);
  GLOAD(ak0a, kB0, 0);
  GLOAD(ak0b, kB0, 16);
  GLOAD(ak1a, kB0, 128);
  GLOAD(ak1b, kB0, 144);
  GLOAD(bh0a, hB1, 0);
  GLOAD(bh0b, hB1, 16);
  GLOAD(bh1a, hB1, 128);
  GLOAD(bh1b, hB1, 144);
  GLOAD(bk0a, kB1, 0);
  GLOAD(bk0b, kB1, 16);
  GLOAD(bk1a, kB1, 128);
  GLOAD(bk1b, kB1, 144);
  __builtin_amdgcn_sched_barrier(0);

  // ---- 2) stage U, V -> bf16 LDS (overlaps the 16 in-flight loads) ----
  const f4* __restrict__ Ug = reinterpret_cast<const f4*>(U);
  const f4* __restrict__ Vg = reinterpret_cast<const f4*>(V);
  s8* __restrict__ Ub8w = reinterpret_cast<s8*>(Ub);
  s8* __restrict__ Vb8w = reinterpret_cast<s8*>(Vb);
  #pragma unroll
  for (int t = 0; t < 2; ++t) {
    const int m  = tid + TPB * t;       // 0..511 chunk id
    const int c  = m >> 3;
    const int sl = m & 7;
    Ub8w[c * 8 + (sl ^ (c & 7))] = pack8(Ug[c * 16 + sl * 2], Ug[c * 16 + sl * 2 + 1]);
    Vb8w[c * 8 + (sl ^ (c & 7))] = pack8(Vg[c * 16 + sl * 2], Vg[c * 16 + sl * 2 + 1]);
  }

  // ---- cc[c] = bias[c] + W[c,:] @ s ----
  if (tid < D) {
    const f4* __restrict__ wr = reinterpret_cast<const f4*>(W + tid * D);
    const f4* __restrict__ sr = reinterpret_cast<const f4*>(s);
    float acc = bias[tid];
    #pragma unroll
    for (int q = 0; q < 16; ++q) {
      const f4 wq = wr[q];
      const f4 sq = sr[q];
      acc = fmaf(wq.x, sq.x, acc);
      acc = fmaf(wq.y, sq.y, acc);
      acc = fmaf(wq.z, sq.z, acc);
      acc = fmaf(wq.w, sq.w, acc);
    }
    cc[tid] = acc;
  }
  __syncthreads();

  // ---- 3) drain asm loads, then consume both row-groups ----
  asm volatile("s_waitcnt vmcnt(0)" ::: "memory");
  __builtin_amdgcn_sched_barrier(0);

  const f4* __restrict__ sg4 = reinterpret_cast<const f4*>(s);
  const f4 sA0 = sg4[2 * g];
  const f4 sA1 = sg4[2 * g + 1];
  const f4 sB0 = sg4[8 + 2 * g];
  const f4 sB1 = sg4[8 + 2 * g + 1];
  const float a = prelu_a[0];
  const s8* __restrict__ Ub8 = reinterpret_cast<const s8*>(Ub);
  const s8* __restrict__ Vb8 = reinterpret_cast<const s8*>(Vb);
  const f4* __restrict__ cc4 = reinterpret_cast<const f4*>(cc);
  const int srcA = ((g >> 1) << 4) + rl;
  const int srcB = srcA + 32;
  const int odd  = g & 1;

  // A-frag LDS indices (shared by both groups)
  const int c0i = 0 * 16 + rl, c1i = 1 * 16 + rl;
  const int c2i = 2 * 16 + rl, c3i = 3 * 16 + rl;

#define CONSUME(P0A, P0B, P1A, P1B, Q0A, Q0B, Q1A, Q1B, RROW)                  \
  {                                                                            \
    float gd = dot4(P0A, Q0A, sA0, 0.0f);                                      \
    gd = dot4(P0B, Q0B, sA1, gd);                                              \
    gd = dot4(P1A, Q1A, sB0, gd);                                              \
    gd = dot4(P1B, Q1B, sB1, gd);                                              \
    const s8 bfh0 = pack8(P0A, P0B);                                           \
    const s8 bfh1 = pack8(P1A, P1B);                                           \
    const s8 bfk0 = pack8(Q0A, Q0B);                                           \
    const s8 bfk1 = pack8(Q1A, Q1B);                                           \
    const f4 A0 = shfl4(P0A, srcA), B0 = shfl4(P0B, srcA);                     \
    const f4 A1 = shfl4(P0A, srcB), B1 = shfl4(P0B, srcB);                     \
    const f4 A2 = shfl4(P1A, srcA), B2 = shfl4(P1B, srcA);                     \
    const f4 A3 = shfl4(P1A, srcB), B3 = shfl4(P1B, srcB);                     \
    const f4 hr0 = odd ? B0 : A0;                                              \
    const f4 hr1 = odd ? B1 : A1;                                              \
    const f4 hr2 = odd ? B2 : A2;                                              \
    const f4 hr3 = odd ? B3 : A3;                                              \
    f4 acc0 = cc4[0 + g];                                                      \
    f4 acc1 = cc4[4 + g];                                                      \
    f4 acc2 = cc4[8 + g];                                                      \
    f4 acc3 = cc4[12 + g];                                                     \
    _Pragma("unroll")                                                          \
    for (int ks = 0; ks < 2; ++ks) {                                           \
      const int asl = ks * 4 + g;                                              \
      const s8 bh = (ks == 0) ? bfh0 : bfh1;                                   \
      const s8 bk = (ks == 0) ? bfk0 : bfk1;                                   \
      const s8 au0 = Ub8[c0i * 8 + (asl ^ (c0i & 7))];                         \
      const s8 au1 = Ub8[c1i * 8 + (asl ^ (c1i & 7))];                         \
      const s8 au2 = Ub8[c2i * 8 + (asl ^ (c2i & 7))];                         \
      const s8 au3 = Ub8[c3i * 8 + (asl ^ (c3i & 7))];                         \
      const s8 av0 = Vb8[c0i * 8 + (asl ^ (c0i & 7))];                         \
      const s8 av1 = Vb8[c1i * 8 + (asl ^ (c1i & 7))];                         \
      const s8 av2 = Vb8[c2i * 8 + (asl ^ (c2i & 7))];                         \
      const s8 av3 = Vb8[c3i * 8 + (asl ^ (c3i & 7))];                         \
      acc0 = __builtin_amdgcn_mfma_f32_16x16x32_bf16(au0, bh, acc0, 0, 0, 0);  \
      acc1 = __builtin_amdgcn_mfma_f32_16x16x32_bf16(au1, bh, acc1, 0, 0, 0);  \
      acc2 = __builtin_amdgcn_mfma_f32_16x16x32_bf16(au2, bh, acc2, 0, 0, 0);  \
      acc3 = __builtin_amdgcn_mfma_f32_16x16x32_bf16(au3, bh, acc3, 0, 0, 0);  \
      acc0 = __builtin_amdgcn_mfma_f32_16x16x32_bf16(av0, bk, acc0, 0, 0, 0);  \
      acc1 = __builtin_amdgcn_mfma_f32_16x16x32_bf16(av1, bk, acc1, 0, 0, 0);  \
      acc2 = __builtin_amdgcn_mfma_f32_16x16x32_bf16(av2, bk, acc2, 0, 0, 0);  \
      acc3 = __builtin_amdgcn_mfma_f32_16x16x32_bf16(av3, bk, acc3, 0, 0, 0);  \
    }                                                                          \
    gd += __shfl_xor(gd, 16);                                                  \
    gd += __shfl_xor(gd, 32);                                                  \
    const float gt = 1.0f / (1.0f + __expf(-gd));                              \
    f4 o0 = fma4s(gt, prelu4(acc0, a), hr0);                                   \
    f4 o1 = fma4s(gt, prelu4(acc1, a), hr1);                                   \
    f4 o2 = fma4s(gt, prelu4(acc2, a), hr2);                                   \
    f4 o3 = fma4s(gt, prelu4(acc3, a), hr3);                                   \
    float ss = o0.x * o0.x + o0.y * o0.y + o0.z * o0.z + o0.w * o0.w;          \
    ss = fmaf(o1.x, o1.x, ss); ss = fmaf(o1.y, o1.y, ss);                      \
    ss = fmaf(o1.z, o1.z, ss); ss = fmaf(o1.w, o1.w, ss);                      \
    ss = fmaf(o2.x, o2.x, ss); ss = fmaf(o2.y, o2.y, ss);                      \
    ss = fmaf(o2.z, o2.z, ss); ss = fmaf(o2.w, o2.w, ss);                      \
    ss = fmaf(o3.x, o3.x, ss); ss = fmaf(o3.y, o3.y, ss);                      \
    ss = fmaf(o3.z, o3.z, ss); ss = fmaf(o3.w, o3.w, ss);                      \
    ss += __shfl_xor(ss, 16);                                                  \
    ss += __shfl_xor(ss, 32);                                                  \
    const float rn = rsqrtf(ss);                                               \
    if ((RROW) < nrem) {                                                       \
      float* __restrict__ orow = out + (size_t)(j0 + (RROW)) * D + g * 4;      \
      *reinterpret_cast<f4*>(orow +  0) = o0 * rn;                             \
      *reinterpret_cast<f4*>(orow + 16) = o1 * rn;                             \
      *reinterpret_cast<f4*>(orow + 32) = o2 * rn;                             \
      *reinterpret_cast<f4*>(orow + 48) = o3 * rn;                             \
    }                                                                          \
  }

  CONSUME(ah0a, ah0b, ah1a, ah1b, ak0a, ak0b, ak1a, ak1b, r0)
  CONSUME(bh0a, bh0b, bh1a, bh1b, bk0a, bk0b, bk1a, bk1b, r1)
#undef CONSUME
}

extern "C" void kernel_launch(void* const* d_in, const int* in_sizes, int n_in,
                              void* d_out, int out_size, void* d_ws, size_t ws_size,
                              hipStream_t stream) {
  const float* s       = (const float*)d_in[0];
  const float* h       = (const float*)d_in[1];
  const float* keys    = (const float*)d_in[2];
  const float* U       = (const float*)d_in[3];
  const float* V       = (const float*)d_in[4];
  const float* W       = (const float*)d_in[5];
  const float* bias    = (const float*)d_in[6];
  const float* prelu_a = (const float*)d_in[7];
  float* out = (float*)d_out;

  const int nblocks = in_sizes[1] / D;
  const int grid = (nblocks + ROWS - 1) / ROWS;
  dmc_fused<<<grid, TPB, 0, stream>>>(h, keys, s, U, V, W, bias, prelu_a, out,
                                      nblocks);
}

// Round 24
// 92.150 us; speedup vs baseline: 1.2206x; 1.2206x over previous
//
#include <hip/hip_runtime.h>

#define D 64
#define ROWS 64
#define TPB 256

typedef float f4 __attribute__((ext_vector_type(4)));
typedef short s8 __attribute__((ext_vector_type(8)));

static __device__ __forceinline__ unsigned short f2bf(float x) {
  union { float f; unsigned u; } v; v.f = x;
  return (unsigned short)((v.u + 0x7FFFu + ((v.u >> 16) & 1u)) >> 16);
}

static __device__ __forceinline__ s8 pack8(f4 a, f4 b) {
  s8 r;
  r[0] = (short)f2bf(a.x); r[1] = (short)f2bf(a.y);
  r[2] = (short)f2bf(a.z); r[3] = (short)f2bf(a.w);
  r[4] = (short)f2bf(b.x); r[5] = (short)f2bf(b.y);
  r[6] = (short)f2bf(b.z); r[7] = (short)f2bf(b.w);
  return r;
}

static __device__ __forceinline__ f4 fma4s(float a, f4 b, f4 c) {
  f4 r;
  r.x = fmaf(a, b.x, c.x);
  r.y = fmaf(a, b.y, c.y);
  r.z = fmaf(a, b.z, c.z);
  r.w = fmaf(a, b.w, c.w);
  return r;
}

static __device__ __forceinline__ f4 prelu4(f4 p, float a) {
  f4 r;
  r.x = p.x >= 0.0f ? p.x : a * p.x;
  r.y = p.y >= 0.0f ? p.y : a * p.y;
  r.z = p.z >= 0.0f ? p.z : a * p.z;
  r.w = p.w >= 0.0f ? p.w : a * p.w;
  return r;
}

static __device__ __forceinline__ float dot4(f4 x, f4 y, f4 z, float acc) {
  acc = fmaf(x.x + y.x, z.x, acc);
  acc = fmaf(x.y + y.y, z.y, acc);
  acc = fmaf(x.z + y.z, z.z, acc);
  acc = fmaf(x.w + y.w, z.w, acc);
  return acc;
}

static __device__ __forceinline__ f4 shfl4(f4 v, int src) {
  f4 r;
  r.x = __shfl(v.x, src);
  r.y = __shfl(v.y, src);
  r.z = __shfl(v.z, src);
  r.w = __shfl(v.w, src);
  return r;
}

// Raw asm 16B load with distinct dest (compiler cannot coalesce/serialize).
// HAZARD (R20/R21/R23): asm dests must never spill — keep the launch_bounds
// VGPR cap margin generous. (256,4) with 60 regs used is the stable point.
#define GLOAD(dst, ptr, OFF) \
  asm volatile("global_load_dwordx4 %0, %1, off offset:" #OFF \
               : "=v"(dst) : "v"(ptr))

// R24 = R19 (the measured optimum, 91.7us) reverted verbatim.
// Structure: dispatch-ordered 64-row tiles (L3-friendly sweep, minimal
// 125/125MB HBM traffic); 8 B-frag loads as one forced asm burst (8-deep
// MLP, overlapped with U/V/cc LDS staging); hr derived via quad shuffles
// (zero duplicate-line requests); MFMA pair on swizzled bf16 LDS A-frags;
// f32 gate/residual/norm. 23 rounds of ablation: traffic, request count,
// MLP depth, occupancy, staging amortization, persistence all probed —
// every deviation from this point regresses (allocator spill or turnover).
__global__ __launch_bounds__(TPB, 4) void dmc_fused(
    const float* __restrict__ h,
    const float* __restrict__ keys,
    const float* __restrict__ s,
    const float* __restrict__ U,
    const float* __restrict__ V,
    const float* __restrict__ W,
    const float* __restrict__ bias,
    const float* __restrict__ prelu_a,
    float* __restrict__ out,
    const int nblocks) {
  __shared__ __align__(16) unsigned short Ub[D * D];  // 8KB bf16, swizzled
  __shared__ __align__(16) unsigned short Vb[D * D];  // 8KB
  __shared__ __align__(16) float cc[D];

  const int tid  = threadIdx.x;
  const int lane = tid & 63;
  const int wv   = tid >> 6;            // 0..3 = batch row-block
  const int g    = lane >> 4;           // 0..3
  const int rl   = lane & 15;           // MFMA n (batch row) / m (U row)
  const int r    = wv * 16 + rl;        // batch row within tile
  const int j0   = blockIdx.x * ROWS;
  const int nrem = nblocks - j0;
  const int rc   = (r < nrem) ? r : (nrem - 1);

  // ---- 1) issue the 8 B-frag loads via asm (8 distinct dests, 2 bases) ----
  const float* hbase = h + (size_t)(j0 + rc) * D;
  const float* kbase = keys + (size_t)(j0 + rc) * D;
  const f4* hB = reinterpret_cast<const f4*>(hbase) + 2 * g;
  const f4* kB = reinterpret_cast<const f4*>(kbase) + 2 * g;

  f4 ph0a, ph0b, ph1a, ph1b, pk0a, pk0b, pk1a, pk1b;
  GLOAD(ph0a, hB, 0);
  GLOAD(ph0b, hB, 16);
  GLOAD(ph1a, hB, 128);
  GLOAD(ph1b, hB, 144);
  GLOAD(pk0a, kB, 0);
  GLOAD(pk0b, kB, 16);
  GLOAD(pk1a, kB, 128);
  GLOAD(pk1b, kB, 144);
  // Pin: staging below must not be hoisted above the asm loads.
  __builtin_amdgcn_sched_barrier(0);

  // ---- 2) stage U, V -> bf16 LDS (overlaps the 8 in-flight loads) ----
  const f4* __restrict__ Ug = reinterpret_cast<const f4*>(U);
  const f4* __restrict__ Vg = reinterpret_cast<const f4*>(V);
  s8* __restrict__ Ub8w = reinterpret_cast<s8*>(Ub);
  s8* __restrict__ Vb8w = reinterpret_cast<s8*>(Vb);
  #pragma unroll
  for (int t = 0; t < 2; ++t) {
    const int m  = tid + TPB * t;       // 0..511 chunk id
    const int c  = m >> 3;
    const int sl = m & 7;
    Ub8w[c * 8 + (sl ^ (c & 7))] = pack8(Ug[c * 16 + sl * 2], Ug[c * 16 + sl * 2 + 1]);
    Vb8w[c * 8 + (sl ^ (c & 7))] = pack8(Vg[c * 16 + sl * 2], Vg[c * 16 + sl * 2 + 1]);
  }

  // ---- cc[c] = bias[c] + W[c,:] @ s ----
  if (tid < D) {
    const f4* __restrict__ wr = reinterpret_cast<const f4*>(W + tid * D);
    const f4* __restrict__ sr = reinterpret_cast<const f4*>(s);
    float acc = bias[tid];
    #pragma unroll
    for (int q = 0; q < 16; ++q) {
      const f4 wq = wr[q];
      const f4 sq = sr[q];
      acc = fmaf(wq.x, sq.x, acc);
      acc = fmaf(wq.y, sq.y, acc);
      acc = fmaf(wq.z, sq.z, acc);
      acc = fmaf(wq.w, sq.w, acc);
    }
    cc[tid] = acc;
  }
  __syncthreads();

  // ---- 3) drain our asm loads, then consume ----
  asm volatile("s_waitcnt vmcnt(0)" ::: "memory");
  __builtin_amdgcn_sched_barrier(0);

  const f4* __restrict__ sg4 = reinterpret_cast<const f4*>(s);
  float gd = dot4(ph0a, pk0a, sg4[2 * g], 0.0f);
  gd = dot4(ph0b, pk0b, sg4[2 * g + 1], gd);
  gd = dot4(ph1a, pk1a, sg4[8 + 2 * g], gd);
  gd = dot4(ph1b, pk1b, sg4[8 + 2 * g + 1], gd);
  const s8 bh0 = pack8(ph0a, ph0b);
  const s8 bh1 = pack8(ph1a, ph1b);
  const s8 bk0 = pack8(pk0a, pk0b);
  const s8 bk1 = pack8(pk1a, pk1b);

  // hr in D-frag layout via quad shuffles (no global reads; R13-verified)
  const int srcA = ((g >> 1) << 4) + rl;
  const int srcB = srcA + 32;
  const int odd  = g & 1;
  const f4 A0 = shfl4(ph0a, srcA), B0 = shfl4(ph0b, srcA);
  const f4 A1 = shfl4(ph0a, srcB), B1 = shfl4(ph0b, srcB);
  const f4 A2 = shfl4(ph1a, srcA), B2 = shfl4(ph1b, srcA);
  const f4 A3 = shfl4(ph1a, srcB), B3 = shfl4(ph1b, srcB);
  const f4 hr0 = odd ? B0 : A0;
  const f4 hr1 = odd ? B1 : A1;
  const f4 hr2 = odd ? B2 : A2;
  const f4 hr3 = odd ? B3 : A3;

  // ---- accumulators from cc ----
  const f4* __restrict__ cc4 = reinterpret_cast<const f4*>(cc);
  f4 acc0 = cc4[0 + g];
  f4 acc1 = cc4[4 + g];
  f4 acc2 = cc4[8 + g];
  f4 acc3 = cc4[12 + g];

  // ---- MFMA: K=64 as 2 slices of 32 (A-frags from swizzled LDS) ----
  const s8* __restrict__ Ub8 = reinterpret_cast<const s8*>(Ub);
  const s8* __restrict__ Vb8 = reinterpret_cast<const s8*>(Vb);
  #pragma unroll
  for (int ks = 0; ks < 2; ++ks) {
    const int asl = ks * 4 + g;
    const s8 bh = (ks == 0) ? bh0 : bh1;
    const s8 bk = (ks == 0) ? bk0 : bk1;
    const int c0i = 0 * 16 + rl, c1i = 1 * 16 + rl;
    const int c2i = 2 * 16 + rl, c3i = 3 * 16 + rl;
    const s8 au0 = Ub8[c0i * 8 + (asl ^ (c0i & 7))];
    const s8 au1 = Ub8[c1i * 8 + (asl ^ (c1i & 7))];
    const s8 au2 = Ub8[c2i * 8 + (asl ^ (c2i & 7))];
    const s8 au3 = Ub8[c3i * 8 + (asl ^ (c3i & 7))];
    const s8 av0 = Vb8[c0i * 8 + (asl ^ (c0i & 7))];
    const s8 av1 = Vb8[c1i * 8 + (asl ^ (c1i & 7))];
    const s8 av2 = Vb8[c2i * 8 + (asl ^ (c2i & 7))];
    const s8 av3 = Vb8[c3i * 8 + (asl ^ (c3i & 7))];
    acc0 = __builtin_amdgcn_mfma_f32_16x16x32_bf16(au0, bh, acc0, 0, 0, 0);
    acc1 = __builtin_amdgcn_mfma_f32_16x16x32_bf16(au1, bh, acc1, 0, 0, 0);
    acc2 = __builtin_amdgcn_mfma_f32_16x16x32_bf16(au2, bh, acc2, 0, 0, 0);
    acc3 = __builtin_amdgcn_mfma_f32_16x16x32_bf16(au3, bh, acc3, 0, 0, 0);
    acc0 = __builtin_amdgcn_mfma_f32_16x16x32_bf16(av0, bk, acc0, 0, 0, 0);
    acc1 = __builtin_amdgcn_mfma_f32_16x16x32_bf16(av1, bk, acc1, 0, 0, 0);
    acc2 = __builtin_amdgcn_mfma_f32_16x16x32_bf16(av2, bk, acc2, 0, 0, 0);
    acc3 = __builtin_amdgcn_mfma_f32_16x16x32_bf16(av3, bk, acc3, 0, 0, 0);
  }

  // ---- gate reduce (lanes of equal rl hold disjoint k-ranges) ----
  gd += __shfl_xor(gd, 16);
  gd += __shfl_xor(gd, 32);
  const float gt = 1.0f / (1.0f + __expf(-gd));
  const float a  = prelu_a[0];

  // ---- gated residual + row norm ----
  f4 o0 = fma4s(gt, prelu4(acc0, a), hr0);
  f4 o1 = fma4s(gt, prelu4(acc1, a), hr1);
  f4 o2 = fma4s(gt, prelu4(acc2, a), hr2);
  f4 o3 = fma4s(gt, prelu4(acc3, a), hr3);

  float ss = o0.x * o0.x + o0.y * o0.y + o0.z * o0.z + o0.w * o0.w;
  ss = fmaf(o1.x, o1.x, ss); ss = fmaf(o1.y, o1.y, ss);
  ss = fmaf(o1.z, o1.z, ss); ss = fmaf(o1.w, o1.w, ss);
  ss = fmaf(o2.x, o2.x, ss); ss = fmaf(o2.y, o2.y, ss);
  ss = fmaf(o2.z, o2.z, ss); ss = fmaf(o2.w, o2.w, ss);
  ss = fmaf(o3.x, o3.x, ss); ss = fmaf(o3.y, o3.y, ss);
  ss = fmaf(o3.z, o3.z, ss); ss = fmaf(o3.w, o3.w, ss);
  ss += __shfl_xor(ss, 16);
  ss += __shfl_xor(ss, 32);
  const float rn = rsqrtf(ss);

  if (r < nrem) {
    float* __restrict__ orow = out + (size_t)(j0 + r) * D + g * 4;
    *reinterpret_cast<f4*>(orow +  0) = o0 * rn;
    *reinterpret_cast<f4*>(orow + 16) = o1 * rn;
    *reinterpret_cast<f4*>(orow + 32) = o2 * rn;
    *reinterpret_cast<f4*>(orow + 48) = o3 * rn;
  }
}

extern "C" void kernel_launch(void* const* d_in, const int* in_sizes, int n_in,
                              void* d_out, int out_size, void* d_ws, size_t ws_size,
                              hipStream_t stream) {
  const float* s       = (const float*)d_in[0];
  const float* h       = (const float*)d_in[1];
  const float* keys    = (const float*)d_in[2];
  const float* U       = (const float*)d_in[3];
  const float* V       = (const float*)d_in[4];
  const float* W       = (const float*)d_in[5];
  const float* bias    = (const float*)d_in[6];
  const float* prelu_a = (const float*)d_in[7];
  float* out = (float*)d_out;

  const int nblocks = in_sizes[1] / D;
  const int grid = (nblocks + ROWS - 1) / ROWS;
  dmc_fused<<<grid, TPB, 0, stream>>>(h, keys, s, U, V, W, bias, prelu_a, out,
                                      nblocks);
}